// Round 1
// 717.969 us; speedup vs baseline: 3.2167x; 3.2167x over previous
//
#include <hip/hip_runtime.h>
#include <math.h>

#define BN 8192
#define ENC 256
#define NCL 32
#define TM 128
#define TK 16
#define LDT 132  // padded leading dim: 16B-aligned rows, conflict-light

// ---------------- K1: per-row sumsq, argmax/max of categorical ----------------
__global__ void prep_kernel(const float* __restrict__ enc, const float* __restrict__ cat,
                            float* __restrict__ sq, float* __restrict__ maxg,
                            int* __restrict__ hard) {
    int w = threadIdx.x >> 6, l = threadIdx.x & 63;
    int row = blockIdx.x * 4 + w;
    const float4* e4 = (const float4*)(enc + (size_t)row * ENC);
    float4 v = e4[l];  // 64 lanes x float4 = 256 floats
    float s = v.x * v.x + v.y * v.y + v.z * v.z + v.w * v.w;
    for (int m = 32; m; m >>= 1) s += __shfl_xor(s, m, 64);

    float cv = (l < NCL) ? cat[(size_t)row * NCL + l] : -__builtin_huge_valf();
    int ci = (l < NCL) ? l : 0x7fffffff;
    for (int m = 32; m; m >>= 1) {
        float ov = __shfl_xor(cv, m, 64);
        int oi = __shfl_xor(ci, m, 64);
        if (ov > cv || (ov == cv && oi < ci)) { cv = ov; ci = oi; }
    }
    if (l == 0) { sq[row] = s; maxg[row] = cv; hard[row] = ci; }
}

// ---------------- K2: 128x128 fp32 tiled GEMM -> dist rows (sqrt'd) ----------------
// C = enc * enc^T ; dist = sqrt(max(sq_i + sq_j - 2*dot, 0)). Writes chunk-local rows.
__global__ __launch_bounds__(256, 4)
void dist_gemm_kernel(const float* __restrict__ enc, const float* __restrict__ sq,
                      float* __restrict__ dist, int row0) {
    __shared__ float As[TK][LDT];  // [k][m] transposed tiles
    __shared__ float Bs[TK][LDT];

    int t = threadIdx.x;
    int tx = t & 15, ty = t >> 4;     // 16x16 thread grid, 8x8 micro-tile each
    int li0 = blockIdx.y * TM;        // chunk-local row base (for dist)
    int gi0 = row0 + li0;             // global row base (for enc/sq)
    int j0 = blockIdx.x * TM;

    float acc[8][8];
#pragma unroll
    for (int a = 0; a < 8; ++a)
#pragma unroll
        for (int b = 0; b < 8; ++b) acc[a][b] = 0.f;

    int r = t >> 1;                   // 0..127: tile row this thread stages
    int cq0 = (t & 1) * 2;            // float4-group 0..3 (two per thread)

    for (int k0 = 0; k0 < ENC; k0 += TK) {
        // issue global loads early (overlap with previous compute)
        const float* pa = enc + (size_t)(gi0 + r) * ENC + k0 + cq0 * 4;
        const float* pb = enc + (size_t)(j0 + r) * ENC + k0 + cq0 * 4;
        float4 va0 = *(const float4*)(pa);
        float4 va1 = *(const float4*)(pa + 4);
        float4 vb0 = *(const float4*)(pb);
        float4 vb1 = *(const float4*)(pb + 4);

        __syncthreads();  // previous compute done before overwriting tiles
        As[cq0 * 4 + 0][r] = va0.x; As[cq0 * 4 + 1][r] = va0.y;
        As[cq0 * 4 + 2][r] = va0.z; As[cq0 * 4 + 3][r] = va0.w;
        As[cq0 * 4 + 4][r] = va1.x; As[cq0 * 4 + 5][r] = va1.y;
        As[cq0 * 4 + 6][r] = va1.z; As[cq0 * 4 + 7][r] = va1.w;
        Bs[cq0 * 4 + 0][r] = vb0.x; Bs[cq0 * 4 + 1][r] = vb0.y;
        Bs[cq0 * 4 + 2][r] = vb0.z; Bs[cq0 * 4 + 3][r] = vb0.w;
        Bs[cq0 * 4 + 4][r] = vb1.x; Bs[cq0 * 4 + 5][r] = vb1.y;
        Bs[cq0 * 4 + 6][r] = vb1.z; Bs[cq0 * 4 + 7][r] = vb1.w;
        __syncthreads();

#pragma unroll
        for (int k = 0; k < TK; ++k) {
            float4 a0 = *(const float4*)&As[k][ty * 8];
            float4 a1 = *(const float4*)&As[k][ty * 8 + 4];
            float4 b0 = *(const float4*)&Bs[k][tx * 8];
            float4 b1 = *(const float4*)&Bs[k][tx * 8 + 4];
            float av[8] = {a0.x, a0.y, a0.z, a0.w, a1.x, a1.y, a1.z, a1.w};
            float bv[8] = {b0.x, b0.y, b0.z, b0.w, b1.x, b1.y, b1.z, b1.w};
#pragma unroll
            for (int a = 0; a < 8; ++a)
#pragma unroll
                for (int b = 0; b < 8; ++b)
                    acc[a][b] = fmaf(av[a], bv[b], acc[a][b]);
        }
    }

    float sqi[8], sqj[8];
#pragma unroll
    for (int a = 0; a < 8; ++a) sqi[a] = sq[gi0 + ty * 8 + a];
#pragma unroll
    for (int b = 0; b < 8; ++b) sqj[b] = sq[j0 + tx * 8 + b];

#pragma unroll
    for (int a = 0; a < 8; ++a) {
        float o[8];
#pragma unroll
        for (int b = 0; b < 8; ++b)
            o[b] = sqrtf(fmaxf(sqi[a] + sqj[b] - 2.0f * acc[a][b], 0.0f));
        float4* dst = (float4*)(dist + (size_t)(li0 + ty * 8 + a) * BN + j0 + tx * 8);
        dst[0] = make_float4(o[0], o[1], o[2], o[3]);
        dst[1] = make_float4(o[4], o[5], o[6], o[7]);
    }
}

// ---------------- K3: exact rank-26 select + counts + entropy ----------------
// 512 threads = 8 waves; 4 rows/block, 2 waves per row, 64 dists per lane (registers).
__global__ __launch_bounds__(512, 4)
void select_kernel(const float* __restrict__ dist, const float* __restrict__ maxg,
                   const int* __restrict__ hard, const int* __restrict__ kptr,
                   float* __restrict__ out, int row0) {
    __shared__ int sbins[4 * NCL];
    __shared__ int scnt[8];

    int t = threadIdx.x, w = t >> 6, l = t & 63;
    int rr = w >> 1, h = w & 1;          // row-in-block, half of row
    int li = blockIdx.x * 4 + rr;        // chunk-local row
    if (t < 4 * NCL) sbins[t] = 0;

    unsigned u[64];
    const float4* rd = (const float4*)(dist + (size_t)li * BN + h * (BN / 2));
#pragma unroll
    for (int e = 0; e < 16; ++e) {
        float4 v = rd[e * 64 + l];
        u[e * 4 + 0] = __float_as_uint(v.x);
        u[e * 4 + 1] = __float_as_uint(v.y);
        u[e * 4 + 2] = __float_as_uint(v.z);
        u[e * 4 + 3] = __float_as_uint(v.w);
    }

    int topn = *kptr + 1;  // 26: thr = sorted[k] = 26th smallest
    // Fixed 31 iterations (range < 2^31) so barriers are uniform across rows.
    unsigned lo = 0u, hi = 0x7F800000u;  // dist >= 0 -> uint compare == float compare
    for (int it = 0; it < 31; ++it) {
        unsigned mid = lo + ((hi - lo) >> 1);
        int cnt = 0;
#pragma unroll
        for (int e = 0; e < 64; ++e) cnt += (u[e] <= mid) ? 1 : 0;
        for (int m = 32; m; m >>= 1) cnt += __shfl_xor(cnt, m, 64);
        __syncthreads();                 // protect previous iteration's scnt reads
        if (l == 0) scnt[w] = cnt;
        __syncthreads();
        int tot = scnt[rr * 2] + scnt[rr * 2 + 1];
        if (lo < hi) { if (tot >= topn) hi = mid; else lo = mid + 1; }
    }
    unsigned thrb = lo;                  // bit pattern of sorted[25]

    // strict < thr, per-cluster counts (rare hits -> LDS atomics)
#pragma unroll
    for (int e = 0; e < 16; ++e) {
#pragma unroll
        for (int c = 0; c < 4; ++c) {
            if (u[e * 4 + c] < thrb) {
                int j = h * (BN / 2) + e * 256 + l * 4 + c;  // global column
                atomicAdd(&sbins[rr * NCL + hard[j]], 1);
            }
        }
    }
    __syncthreads();

    // entropy epilogue: even wave of each row, lanes 0..31 = clusters
    if (h == 0 && l < NCL) {
        int cnt = sbins[rr * NCL + l];
        int n = cnt;
        for (int m = 16; m; m >>= 1) n += __shfl_xor(n, m, 64);
        float nf = (float)n;
        float b = (float)cnt / nf;
        float term = -b * logf(b + 1e-5f);
        for (int m = 16; m; m >>= 1) term += __shfl_xor(term, m, 64);
        if (l == 0) out[row0 + li] = term * maxg[row0 + li];
    }
}

extern "C" void kernel_launch(void* const* d_in, const int* in_sizes, int n_in,
                              void* d_out, int out_size, void* d_ws, size_t ws_size,
                              hipStream_t stream) {
    const float* enc = (const float*)d_in[0];
    const float* cat = (const float*)d_in[1];
    const int* kptr = (const int*)d_in[2];
    float* out = (float*)d_out;

    float* sq = (float*)d_ws;
    float* maxg = sq + BN;
    int* hard = (int*)(maxg + BN);
    float* dist = (float*)((char*)d_ws + 3 * (size_t)BN * sizeof(float));

    // Chunk rows so the dist buffer fits the workspace (full matrix = 268 MB).
    size_t head = 3 * (size_t)BN * sizeof(float);
    size_t avail = ws_size > head ? ws_size - head : 0;
    long max_rows = (long)(avail / ((size_t)BN * sizeof(float)));
    int chunk = (int)((max_rows / TM) * TM);
    if (chunk > BN) chunk = BN;
    if (chunk < TM) chunk = TM;

    prep_kernel<<<BN / 4, 256, 0, stream>>>(enc, cat, sq, maxg, hard);

    for (int row0 = 0; row0 < BN; row0 += chunk) {
        int rows = BN - row0 < chunk ? BN - row0 : chunk;
        dim3 g(BN / TM, rows / TM);
        dist_gemm_kernel<<<g, 256, 0, stream>>>(enc, sq, dist, row0);
        select_kernel<<<rows / 4, 512, 0, stream>>>(dist, maxg, hard, kptr, out, row0);
    }
}

// Round 2
// 423.841 us; speedup vs baseline: 5.4490x; 1.6940x over previous
//
#include <hip/hip_runtime.h>
#include <math.h>

#define BN 8192
#define ENC 256
#define NCL 32
#define TM 128

typedef __attribute__((ext_vector_type(8))) short short8;   // bf16x8 fragment
typedef __attribute__((ext_vector_type(4))) float f32x4;

__device__ __forceinline__ ushort f2bf(float x) {           // RNE float->bf16
    unsigned b = __float_as_uint(x);
    return (ushort)((b + 0x7FFFu + ((b >> 16) & 1u)) >> 16);
}

__device__ __forceinline__ void async16(void* lds, const void* g) {
    __builtin_amdgcn_global_load_lds(
        (const __attribute__((address_space(1))) unsigned*)g,
        (__attribute__((address_space(3))) unsigned*)lds, 16, 0, 0);
}

// ---------------- K1: sumsq + cat argmax + bf16 hi/lo split (granule-swizzled) ----------
// Swizzle: within each 64-elem K-step, 16B granule g -> g ^ (row&7). Linear
// global_load_lds then lands the XOR-swizzled layout in LDS (rule #21: swizzle
// the SOURCE, read with the same XOR).
__global__ void prep_kernel(const float* __restrict__ enc, const float* __restrict__ cat,
                            float* __restrict__ sq, float* __restrict__ maxg,
                            int* __restrict__ hard, ushort* __restrict__ eh,
                            ushort* __restrict__ el) {
    int w = threadIdx.x >> 6, l = threadIdx.x & 63;
    int row = blockIdx.x * 4 + w;
    const float4* e4 = (const float4*)(enc + (size_t)row * ENC);
    float4 v = e4[l];  // elements 4l..4l+3
    float s = v.x * v.x + v.y * v.y + v.z * v.z + v.w * v.w;
    for (int m = 32; m; m >>= 1) s += __shfl_xor(s, m, 64);

    ushort4 hh, ll;
    hh.x = f2bf(v.x); ll.x = f2bf(v.x - __uint_as_float((unsigned)hh.x << 16));
    hh.y = f2bf(v.y); ll.y = f2bf(v.y - __uint_as_float((unsigned)hh.y << 16));
    hh.z = f2bf(v.z); ll.z = f2bf(v.z - __uint_as_float((unsigned)hh.z << 16));
    hh.w = f2bf(v.w); ll.w = f2bf(v.w - __uint_as_float((unsigned)hh.w << 16));
    int g = l >> 1;                                   // original 16B granule 0..31
    int gs = (g & 24) | ((g & 7) ^ (row & 7));        // swizzled granule
    int kp = gs * 8 + (l & 1) * 4;                    // element offset in row
    *(ushort4*)(eh + (size_t)row * ENC + kp) = hh;
    *(ushort4*)(el + (size_t)row * ENC + kp) = ll;

    float cv = (l < NCL) ? cat[(size_t)row * NCL + l] : -__builtin_huge_valf();
    int ci = (l < NCL) ? l : 0x7fffffff;
    for (int m = 32; m; m >>= 1) {
        float ov = __shfl_xor(cv, m, 64);
        int oi = __shfl_xor(ci, m, 64);
        if (ov > cv || (ov == cv && oi < ci)) { cv = ov; ci = oi; }
    }
    if (l == 0) { sq[row] = s; maxg[row] = cv; hard[row] = ci; }
}

// ---------------- K2: split-bf16 MFMA distance GEMM ----------------
// dot = hi.hi + hi.lo + lo.hi (lo.lo dropped, ~2^-18 rel). 128x128 tile, BK=64,
// 4 waves (2x2), each wave 64x64 via 4x4 frags of 16x16x32 bf16 MFMA.
__global__ __launch_bounds__(256, 2)
void dist_mfma_kernel(const ushort* __restrict__ eh, const ushort* __restrict__ el,
                      const float* __restrict__ sq, float* __restrict__ dist, int row0) {
    __shared__ __align__(16) ushort lds[4 * TM * 64];  // 64 KB: Ah Al Bh Bl
    ushort* Ah = lds;
    ushort* Al = lds + TM * 64;
    ushort* Bh = lds + 2 * TM * 64;
    ushort* Bl = lds + 3 * TM * 64;

    int t = threadIdx.x, w = t >> 6, l = t & 63;
    int wm = w >> 1, wn = w & 1;
    int li0 = blockIdx.y * TM;         // chunk-local A rows (dist)
    int gi0 = row0 + li0;              // global A rows
    int j0 = blockIdx.x * TM;          // global B rows / dist cols

    f32x4 acc[4][4];
#pragma unroll
    for (int m = 0; m < 4; ++m)
#pragma unroll
        for (int n = 0; n < 4; ++n) acc[m][n] = (f32x4){0.f, 0.f, 0.f, 0.f};

    int srow = w * 32 + (l >> 3);      // staging row (+ q*8), wave covers 32 rows
    int selem = (l & 7) * 8;           // granule elem offset within K-step slice

    for (int k0 = 0; k0 < ENC; k0 += 64) {
        __syncthreads();               // LDS reads of previous step done
#pragma unroll
        for (int q = 0; q < 4; ++q) {
            int r = srow + q * 8;
            size_t ga = (size_t)(gi0 + r) * ENC + k0 + selem;
            size_t gb = (size_t)(j0 + r) * ENC + k0 + selem;
            int ldo = (w * 4 + q) * 512;  // ushort offset: 64 lanes x 16B
            async16(Ah + ldo, eh + ga);
            async16(Al + ldo, el + ga);
            async16(Bh + ldo, eh + gb);
            async16(Bl + ldo, el + gb);
        }
        __syncthreads();               // drains vmcnt (compiler) -> tiles ready

#pragma unroll
        for (int h = 0; h < 2; ++h) {  // two K=32 halves of the K-step
            short8 ah[4], al4[4], bh[4], bl4[4];
#pragma unroll
            for (int m = 0; m < 4; ++m) {
                int R = wm * 64 + m * 16 + (l & 15);
                int gq = (h * 4 + (l >> 4)) ^ (R & 7);   // un-swizzle on read
                ah[m]  = *(const short8*)(Ah + R * 64 + gq * 8);
                al4[m] = *(const short8*)(Al + R * 64 + gq * 8);
            }
#pragma unroll
            for (int n = 0; n < 4; ++n) {
                int R = wn * 64 + n * 16 + (l & 15);
                int gq = (h * 4 + (l >> 4)) ^ (R & 7);
                bh[n]  = *(const short8*)(Bh + R * 64 + gq * 8);
                bl4[n] = *(const short8*)(Bl + R * 64 + gq * 8);
            }
#pragma unroll
            for (int m = 0; m < 4; ++m)
#pragma unroll
                for (int n = 0; n < 4; ++n) {
                    acc[m][n] = __builtin_amdgcn_mfma_f32_16x16x32_bf16(ah[m],  bh[n],  acc[m][n], 0, 0, 0);
                    acc[m][n] = __builtin_amdgcn_mfma_f32_16x16x32_bf16(ah[m],  bl4[n], acc[m][n], 0, 0, 0);
                    acc[m][n] = __builtin_amdgcn_mfma_f32_16x16x32_bf16(al4[m], bh[n],  acc[m][n], 0, 0, 0);
                }
        }
    }

    // epilogue: C/D layout col=lane&15, row=(lane>>4)*4+reg (m89-verified)
    float sqi[16], sqj[4];
#pragma unroll
    for (int m = 0; m < 4; ++m)
#pragma unroll
        for (int r = 0; r < 4; ++r)
            sqi[m * 4 + r] = sq[gi0 + wm * 64 + m * 16 + (l >> 4) * 4 + r];
#pragma unroll
    for (int n = 0; n < 4; ++n) sqj[n] = sq[j0 + wn * 64 + n * 16 + (l & 15)];

#pragma unroll
    for (int m = 0; m < 4; ++m)
#pragma unroll
        for (int n = 0; n < 4; ++n)
#pragma unroll
            for (int r = 0; r < 4; ++r) {
                float d2 = sqi[m * 4 + r] + sqj[n] - 2.f * acc[m][n][r];
                size_t off = (size_t)(li0 + wm * 64 + m * 16 + (l >> 4) * 4 + r) * BN
                           + (size_t)(j0 + wn * 64 + n * 16 + (l & 15));
                dist[off] = sqrtf(fmaxf(d2, 0.f));
            }
}

// ---------------- K3: barrier-free rank-26 select, one wave per row ----------------
__global__ __launch_bounds__(256, 2)
void select_kernel(const float* __restrict__ dist, const float* __restrict__ maxg,
                   const int* __restrict__ hard, const int* __restrict__ kptr,
                   float* __restrict__ out, int row0) {
    __shared__ int sbins[4 * NCL];
    int t = threadIdx.x, w = t >> 6, l = t & 63;
    int li = blockIdx.x * 4 + w;       // chunk-local row, one wave per row
    if (l < NCL) sbins[w * NCL + l] = 0;   // own wave's bins only: no barrier

    unsigned u[128];
    const float4* rd = (const float4*)(dist + (size_t)li * BN);
#pragma unroll
    for (int e = 0; e < 32; ++e) {
        float4 v = rd[e * 64 + l];
        u[e * 4 + 0] = __float_as_uint(v.x);
        u[e * 4 + 1] = __float_as_uint(v.y);
        u[e * 4 + 2] = __float_as_uint(v.z);
        u[e * 4 + 3] = __float_as_uint(v.w);
    }

    // row min/max -> tight search range (dist>=0: uint order == float order)
    unsigned mn = u[0], mx = u[0];
#pragma unroll
    for (int e = 1; e < 128; ++e) {
        mn = u[e] < mn ? u[e] : mn;
        mx = u[e] > mx ? u[e] : mx;
    }
    for (int m = 32; m; m >>= 1) {
        unsigned on = (unsigned)__shfl_xor((int)mn, m, 64);
        unsigned ox = (unsigned)__shfl_xor((int)mx, m, 64);
        mn = on < mn ? on : mn;
        mx = ox > mx ? ox : mx;
    }

    int topn = *kptr + 1;  // 26: thr = sorted[k]
    unsigned lo = mn, hi = mx;
    while (lo < hi) {      // wave-uniform: scalar branch, no block sync
        unsigned mid = lo + ((hi - lo) >> 1);
        int cnt = 0;
#pragma unroll
        for (int e = 0; e < 128; ++e)
            cnt += __popcll(__ballot(u[e] <= mid));  // v_cmp + s_bcnt1 (SALU)
        if (cnt >= topn) hi = mid; else lo = mid + 1;
    }
    unsigned thrb = lo;    // bit pattern of sorted[25]

#pragma unroll
    for (int e = 0; e < 32; ++e)
#pragma unroll
        for (int c = 0; c < 4; ++c)
            if (u[e * 4 + c] < thrb)
                atomicAdd(&sbins[w * NCL + hard[e * 256 + l * 4 + c]], 1);
    __syncthreads();       // cheap safety; bins are wave-local

    if (l < NCL) {
        int cnt = sbins[w * NCL + l];
        int n = cnt;
        for (int m = 16; m; m >>= 1) n += __shfl_xor(n, m, 64);
        float nf = (float)n;
        float b = (float)cnt / nf;
        float term = -b * logf(b + 1e-5f);
        for (int m = 16; m; m >>= 1) term += __shfl_xor(term, m, 64);
        if (l == 0) out[row0 + li] = term * maxg[row0 + li];
    }
}

extern "C" void kernel_launch(void* const* d_in, const int* in_sizes, int n_in,
                              void* d_out, int out_size, void* d_ws, size_t ws_size,
                              hipStream_t stream) {
    const float* enc = (const float*)d_in[0];
    const float* cat = (const float*)d_in[1];
    const int* kptr = (const int*)d_in[2];
    float* out = (float*)d_out;

    float* sq = (float*)d_ws;
    float* maxg = sq + BN;
    int* hard = (int*)(maxg + BN);
    ushort* eh = (ushort*)(hard + BN);
    ushort* el = eh + (size_t)BN * ENC;
    float* dist = (float*)(el + (size_t)BN * ENC);

    size_t head = (size_t)((char*)dist - (char*)d_ws);
    size_t avail = ws_size > head ? ws_size - head : 0;
    long max_rows = (long)(avail / ((size_t)BN * sizeof(float)));
    int chunk = (int)((max_rows / TM) * TM);
    if (chunk > BN) chunk = BN;
    if (chunk < TM) chunk = TM;

    prep_kernel<<<BN / 4, 256, 0, stream>>>(enc, cat, sq, maxg, hard, eh, el);

    for (int row0 = 0; row0 < BN; row0 += chunk) {
        int rows = BN - row0 < chunk ? BN - row0 : chunk;
        dim3 g(BN / TM, rows / TM);
        dist_mfma_kernel<<<g, 256, 0, stream>>>(eh, el, sq, dist, row0);
        select_kernel<<<rows / 4, 256, 0, stream>>>(dist, maxg, hard, kptr, out, row0);
    }
}